// Round 8
// baseline (323.473 us; speedup 1.0000x reference)
//
#include <hip/hip_runtime.h>
#include <hip/hip_bf16.h>
#include <math.h>

typedef __bf16 bf16_t;
typedef __bf16 bf16x4 __attribute__((ext_vector_type(4)));
typedef __bf16 bf16x8 __attribute__((ext_vector_type(8)));
typedef float f32x4 __attribute__((ext_vector_type(4)));

#define LOG2E 1.44269504088896340736f

// async global->LDS DMA, 16B per lane; LDS dest = wave-uniform base + lane*16
#define GL2LDS(g, l)                                                     \
  __builtin_amdgcn_global_load_lds(                                      \
      (const __attribute__((address_space(1))) unsigned int*)(g),        \
      (__attribute__((address_space(3))) unsigned int*)(l), 16, 0, 0)

// ------------- convert f32 -> bf16, 8 elems/thread ------------------------
__global__ __launch_bounds__(256) void convert_f32_bf16(const float* __restrict__ in,
                                                        bf16_t* __restrict__ out) {
  const size_t idx = (size_t)(blockIdx.x * 256 + threadIdx.x) * 8;
  f32x4 a = *(const f32x4*)&in[idx];
  f32x4 b = *(const f32x4*)&in[idx + 4];
  bf16x8 v;
#pragma unroll
  for (int i = 0; i < 4; i++) { v[i] = (bf16_t)a[i]; v[i + 4] = (bf16_t)b[i]; }
  *(bf16x8*)&out[idx] = v;
}

// ------------- transpose+convert: in f32 [R][C] -> out bf16 [C][R] --------
__global__ __launch_bounds__(256) void transpose_f32_bf16(const float* __restrict__ in,
                                                          bf16_t* __restrict__ out,
                                                          int R, int C) {
  __shared__ bf16_t t[64][65];
  const int c0 = blockIdx.x * 64, r0 = blockIdx.y * 64;
  const int tx = threadIdx.x, ty = threadIdx.y;  // 64 x 4
#pragma unroll
  for (int i = 0; i < 16; i++) {
    int r = ty + i * 4;
    t[r][tx] = (bf16_t)in[(size_t)(r0 + r) * C + c0 + tx];
  }
  __syncthreads();
#pragma unroll
  for (int i = 0; i < 16; i++) {
    int r = ty + i * 4;
    out[(size_t)(c0 + r) * R + r0 + tx] = t[tx][r];
  }
}

// ---------------- 128xBN MFMA GEMM, global_load_lds staging ---------------
// A bf16 [M][1024], Bt bf16 [N][1024]. LDS unpadded rowsx64, XOR-swizzled:
// LDS chunk (r, c) holds global chunk (r, c ^ (r&7)) -> conflict-free b128
// frag reads while staging stays wave-contiguous for the DMA.
// Wave layout: wm=(w&1)*64 (m-half), wn=(w>>1)*(BN/2) (n-half) -- each wave
// computes 4 m-frags x (BN/32) n-frags.  [R7 bug was BN/4 here]
// MODE 0 (BN=128): epilogue scatters qkv into Q(pre-scaled)/K [B][H][N][64],
//                  Vt [B][H][64][N]
// MODE 1 (BN=64):  epilogue adds f32 bias, writes f32 [M][1024]
template <int MODE, int BN>
__global__ __launch_bounds__(256) void gemm128(const bf16_t* __restrict__ A,
                                               const bf16_t* __restrict__ Bt,
                                               bf16_t* __restrict__ Qb,
                                               bf16_t* __restrict__ Kb,
                                               bf16_t* __restrict__ Vtb,
                                               const float* __restrict__ bias,
                                               float* __restrict__ Out) {
  constexpr int K = 1024;
  constexpr int NT = BN / 32;       // B n-frags per wave
  constexpr int NB = BN / 32;       // B staging chunks per thread
  __shared__ __align__(16) bf16_t As[128 * 64];
  __shared__ __align__(16) bf16_t Bs[BN * 64];
  const int m0 = blockIdx.y * 128, n0 = blockIdx.x * BN;
  const int tid = threadIdx.x;
  const int w = tid >> 6, l = tid & 63;
  const int lr = l & 15, lq = l >> 4;
  const int lrx = lr & 7;
  const int wm = (w & 1) * 64, wn = (w >> 1) * (BN / 2);
  // staging: chunk c = i*256+tid covers row r=c>>3, source chunk (c&7)^(r&7)
  int sR[4], sC[4];
#pragma unroll
  for (int i = 0; i < 4; i++) {
    sR[i] = (i * 256 + tid) >> 3;
    sC[i] = ((tid & 7) ^ (sR[i] & 7)) * 8;
  }
  f32x4 acc[4][NT] = {};

  for (int k0 = 0; k0 < K; k0 += 64) {
#pragma unroll
    for (int i = 0; i < 4; i++) {
      const int ldsoff = (i * 256 + w * 64) * 8;
      GL2LDS(&A[(size_t)(m0 + sR[i]) * K + k0 + sC[i]], &As[ldsoff]);
    }
#pragma unroll
    for (int i = 0; i < NB; i++) {
      const int ldsoff = (i * 256 + w * 64) * 8;
      GL2LDS(&Bt[(size_t)(n0 + sR[i]) * K + k0 + sC[i]], &Bs[ldsoff]);
    }
    __syncthreads();
#pragma unroll
    for (int ks = 0; ks < 2; ks++) {
      const int g = ks * 4 + lq;
      const int sw = ((g ^ lrx) << 3);
      bf16x8 af[4], bfr[NT];
#pragma unroll
      for (int mt = 0; mt < 4; mt++)
        af[mt] = *(const bf16x8*)&As[((wm + mt * 16 + lr) << 6) + sw];
#pragma unroll
      for (int nt = 0; nt < NT; nt++)
        bfr[nt] = *(const bf16x8*)&Bs[((wn + nt * 16 + lr) << 6) + sw];
#pragma unroll
      for (int mt = 0; mt < 4; mt++)
#pragma unroll
        for (int nt = 0; nt < NT; nt++)
          acc[mt][nt] = __builtin_amdgcn_mfma_f32_16x16x32_bf16(af[mt], bfr[nt],
                                                                acc[mt][nt], 0, 0, 0);
    }
    __syncthreads();
  }

#pragma unroll
  for (int mt = 0; mt < 4; mt++)
#pragma unroll
    for (int nt = 0; nt < NT; nt++)
#pragma unroll
      for (int i = 0; i < 4; i++) {
        int m = m0 + wm + mt * 16 + lq * 4 + i;   // C/D: row=(lane>>4)*4+i
        int c = n0 + wn + nt * 16 + lr;           //      col=lane&15
        float v = acc[mt][nt][i];
        if (MODE == 1) {
          Out[(size_t)m * 1024 + c] = v + bias[c];
        } else {
          int b = m >> 10, n = m & 1023;
          int which = c >> 10, cc = c & 1023;
          int hh = cc >> 6, d = cc & 63;
          size_t qk = ((size_t)((b * 16 + hh) * 1024 + n)) * 64 + d;
          if (which == 0)
            Qb[qk] = (bf16_t)(v * (0.125f * LOG2E));  // fold softmax scale+log2e
          else if (which == 1)
            Kb[qk] = (bf16_t)v;
          else
            Vtb[((size_t)((b * 16 + hh) * 64 + d)) * 1024 + n] = (bf16_t)v;
        }
      }
}

// ---------------- flash attention v4: DMA staging, one-pass softmax -------
// 1 block = (b, h, 128-query tile); 4 waves x 32 queries (2 m-frags each).
// Block remap: bid = qt*128 + (b*16+h) so a head's 8 q-tiles share an XCD
// (round-robin heuristic) -> KV working set/XCD ~4MB ~= L2.
// K/V staged via global_load_lds into unpadded 64-stride LDS with XOR source
// swizzle (conflict-free b128 frag reads); double-buffered, 1 barrier/iter.
// Q pre-scaled by 0.125*log2e -> p = exp2(s). Rowsum via ones-B-frag MFMA.
#define PS 76
__global__ __launch_bounds__(256) void attn128(const bf16_t* __restrict__ Qb,
                                               const bf16_t* __restrict__ Kb,
                                               const bf16_t* __restrict__ Vtb,
                                               bf16_t* __restrict__ Ob) {
  __shared__ __align__(16) bf16_t Ks[2][64 * 64];
  __shared__ __align__(16) bf16_t Vs[2][64 * 64];
  __shared__ __align__(16) bf16_t Pl[4 * 32 * PS];
  const int bid = blockIdx.x;
  const int qt = bid >> 7, idx = bid & 127;  // XCD-locality remap
  const int h = idx & 15, b = idx >> 4;
  const bf16_t* Qh = Qb + (size_t)((b * 16 + h) * 1024) * 64;
  const bf16_t* Kh = Kb + (size_t)((b * 16 + h) * 1024) * 64;
  const bf16_t* Vh = Vtb + (size_t)((b * 16 + h) * 64) * 1024;  // [64][1024]
  const int tid = threadIdx.x, w = tid >> 6, l = tid & 63;
  const int lr = l & 15, lq = l >> 4;
  const int lrx = lr & 7;
  const int q0 = qt * 128 + w * 32;

  bf16x8 onesf;
#pragma unroll
  for (int i = 0; i < 8; i++) onesf[i] = (lr == 0) ? (bf16_t)1.0f : (bf16_t)0.0f;

  // staging: thread covers chunks tid (row sr) and tid+256 (row sr+32);
  // source col-chunk swizzled by row&7 ((sr+32)&7 == sr&7).
  const int sr = tid >> 3;
  const int scc = ((tid & 7) ^ (sr & 7)) * 8;
  const int ldsA = w * 512;          // wave chunk-base (elems) for chunk tid
  const int ldsB = 2048 + w * 512;   // for chunk tid+256

  bf16x8 qf[2][2];
#pragma unroll
  for (int mt = 0; mt < 2; mt++)
#pragma unroll
    for (int ks = 0; ks < 2; ks++)
      qf[mt][ks] = *(const bf16x8*)&Qh[(size_t)(q0 + mt * 16 + lr) * 64 + ks * 32 + lq * 8];

  // prologue: DMA tile 0 into buf 0
  GL2LDS(&Kh[(size_t)sr * 64 + scc], &Ks[0][ldsA]);
  GL2LDS(&Kh[(size_t)(sr + 32) * 64 + scc], &Ks[0][ldsB]);
  GL2LDS(&Vh[(size_t)sr * 1024 + scc], &Vs[0][ldsA]);
  GL2LDS(&Vh[(size_t)(sr + 32) * 1024 + scc], &Vs[0][ldsB]);
  __syncthreads();

  f32x4 o[2][4] = {};
  f32x4 o5[2] = {};
  bf16_t* pw = &Pl[w * 32 * PS];

  for (int it = 0; it < 16; ++it) {
    const int buf = it & 1;
    if (it < 15) {  // DMA next tile into the other buffer
      const int jn = (it + 1) * 64;
      GL2LDS(&Kh[(size_t)(jn + sr) * 64 + scc], &Ks[buf ^ 1][ldsA]);
      GL2LDS(&Kh[(size_t)(jn + sr + 32) * 64 + scc], &Ks[buf ^ 1][ldsB]);
      GL2LDS(&Vh[(size_t)sr * 1024 + jn + scc], &Vs[buf ^ 1][ldsA]);
      GL2LDS(&Vh[(size_t)(sr + 32) * 1024 + jn + scc], &Vs[buf ^ 1][ldsB]);
    }
    // S = Q K^T  (2 m-tiles x 4 n-tiles), swizzled frag reads
    f32x4 s[2][4] = {};
#pragma unroll
    for (int ks = 0; ks < 2; ks++) {
      const int sw = (((ks * 4 + lq) ^ lrx) << 3);
#pragma unroll
      for (int nt = 0; nt < 4; nt++) {
        bf16x8 kf = *(const bf16x8*)&Ks[buf][((nt * 16 + lr) << 6) + sw];
#pragma unroll
        for (int mt = 0; mt < 2; mt++)
          s[mt][nt] = __builtin_amdgcn_mfma_f32_16x16x32_bf16(qf[mt][ks], kf, s[mt][nt], 0, 0, 0);
      }
    }
    // p = exp2(s); pack to wave-private LDS in A-layout
#pragma unroll
    for (int mt = 0; mt < 2; mt++)
#pragma unroll
      for (int nt = 0; nt < 4; nt++)
#pragma unroll
        for (int i = 0; i < 4; i++)
          pw[(mt * 16 + lq * 4 + i) * PS + nt * 16 + lr] = (bf16_t)exp2f(s[mt][nt][i]);
    // O += P V ; o5 += P * ones. In-wave LDS RAW ordered by lgkmcnt.
#pragma unroll
    for (int ks = 0; ks < 2; ks++) {
      const int sw = (((ks * 4 + lq) ^ lrx) << 3);
      bf16x8 af[2];
#pragma unroll
      for (int mt = 0; mt < 2; mt++)
        af[mt] = *(const bf16x8*)&pw[(mt * 16 + lr) * PS + ks * 32 + lq * 8];
#pragma unroll
      for (int nt = 0; nt < 4; nt++) {
        bf16x8 vf = *(const bf16x8*)&Vs[buf][((nt * 16 + lr) << 6) + sw];
#pragma unroll
        for (int mt = 0; mt < 2; mt++)
          o[mt][nt] = __builtin_amdgcn_mfma_f32_16x16x32_bf16(af[mt], vf, o[mt][nt], 0, 0, 0);
      }
#pragma unroll
      for (int mt = 0; mt < 2; mt++)
        o5[mt] = __builtin_amdgcn_mfma_f32_16x16x32_bf16(af[mt], onesf, o5[mt], 0, 0, 0);
    }
    __syncthreads();  // drains DMA (vmcnt) + LDS; flips buffers
  }
  // epilogue: broadcast denominator from col-0 lanes, divide, store
#pragma unroll
  for (int mt = 0; mt < 2; mt++)
#pragma unroll
    for (int i = 0; i < 4; i++) {
      float lsum = __shfl(o5[mt][i], lq * 16);  // lane (lq,lr=0) holds rowsum
      float inv = 1.0f / lsum;
      int grow = b * 1024 + q0 + mt * 16 + lq * 4 + i;
#pragma unroll
      for (int nt = 0; nt < 4; nt++) {
        int col = h * 64 + nt * 16 + lr;
        Ob[(size_t)grow * 1024 + col] = (bf16_t)(o[mt][nt][i] * inv);
      }
    }
}

extern "C" void kernel_launch(void* const* d_in, const int* in_sizes, int n_in,
                              void* d_out, int out_size, void* d_ws, size_t ws_size,
                              hipStream_t stream) {
  const float* x     = (const float*)d_in[0];  // [8,1024,1024] f32
  const float* w_qkv = (const float*)d_in[1];  // [1024,3072] f32
  const float* w_out = (const float*)d_in[2];  // [1024,1024] f32
  const float* b_out = (const float*)d_in[3];  // [1024] f32
  float* out = (float*)d_out;                  // [8,1024,1024] f32

  bf16_t* ws = (bf16_t*)d_ws;
  const size_t SZ = (size_t)8 * 1024 * 1024;  // elems per 16MB buffer
  bf16_t* Qb  = ws;            // [B][H][N][64]  (pre-scaled)
  bf16_t* Kb  = Qb + SZ;       // [B][H][N][64]
  bf16_t* Vtb = Kb + SZ;       // [B][H][64][N]
  bf16_t* Ob  = Vtb + SZ;      // [B*N][H*64]; also aliases Xb (dead after gemm0)
  bf16_t* Wqt = Ob + SZ;       // [3072][1024]
  bf16_t* Wot = Wqt + (size_t)3072 * 1024;  // [1024][1024]
  bf16_t* Xb  = Ob;            // x as bf16 [8192][1024]
  // total ws use: 72 MB

  hipLaunchKernelGGL(convert_f32_bf16, dim3(4096), dim3(256), 0, stream, x, Xb);
  hipLaunchKernelGGL(transpose_f32_bf16, dim3(48, 16), dim3(64, 4), 0, stream,
                     w_qkv, Wqt, 1024, 3072);
  hipLaunchKernelGGL(transpose_f32_bf16, dim3(16, 16), dim3(64, 4), 0, stream,
                     w_out, Wot, 1024, 1024);
  hipLaunchKernelGGL((gemm128<0, 128>), dim3(24, 64), dim3(256), 0, stream,
                     Xb, Wqt, Qb, Kb, Vtb, (const float*)nullptr, (float*)nullptr);
  hipLaunchKernelGGL(attn128, dim3(1024), dim3(256), 0, stream, Qb, Kb, Vtb, Ob);
  hipLaunchKernelGGL((gemm128<1, 64>), dim3(16, 64), dim3(256), 0, stream,
                     Ob, Wot, (bf16_t*)nullptr, (bf16_t*)nullptr, (bf16_t*)nullptr,
                     b_out, out);
}

// Round 9
// 286.138 us; speedup vs baseline: 1.1305x; 1.1305x over previous
//
#include <hip/hip_runtime.h>
#include <hip/hip_bf16.h>
#include <math.h>

typedef __bf16 bf16_t;
typedef __bf16 bf16x4 __attribute__((ext_vector_type(4)));
typedef __bf16 bf16x8 __attribute__((ext_vector_type(8)));
typedef float f32x4 __attribute__((ext_vector_type(4)));

#define LOG2E 1.44269504088896340736f

// async global->LDS DMA, 16B per lane; LDS dest = wave-uniform base + lane*16
#define GL2LDS(g, l)                                                     \
  __builtin_amdgcn_global_load_lds(                                      \
      (const __attribute__((address_space(1))) unsigned int*)(g),        \
      (__attribute__((address_space(3))) unsigned int*)(l), 16, 0, 0)

// ------------- convert f32 -> bf16, 8 elems/thread ------------------------
__global__ __launch_bounds__(256) void convert_f32_bf16(const float* __restrict__ in,
                                                        bf16_t* __restrict__ out) {
  const size_t idx = (size_t)(blockIdx.x * 256 + threadIdx.x) * 8;
  f32x4 a = *(const f32x4*)&in[idx];
  f32x4 b = *(const f32x4*)&in[idx + 4];
  bf16x8 v;
#pragma unroll
  for (int i = 0; i < 4; i++) { v[i] = (bf16_t)a[i]; v[i + 4] = (bf16_t)b[i]; }
  *(bf16x8*)&out[idx] = v;
}

// ------------- transpose+convert: in f32 [R][C] -> out bf16 [C][R] --------
__global__ __launch_bounds__(256) void transpose_f32_bf16(const float* __restrict__ in,
                                                          bf16_t* __restrict__ out,
                                                          int R, int C) {
  __shared__ bf16_t t[64][65];
  const int c0 = blockIdx.x * 64, r0 = blockIdx.y * 64;
  const int tx = threadIdx.x, ty = threadIdx.y;  // 64 x 4
#pragma unroll
  for (int i = 0; i < 16; i++) {
    int r = ty + i * 4;
    t[r][tx] = (bf16_t)in[(size_t)(r0 + r) * C + c0 + tx];
  }
  __syncthreads();
#pragma unroll
  for (int i = 0; i < 16; i++) {
    int r = ty + i * 4;
    out[(size_t)(c0 + r) * R + r0 + tx] = t[tx][r];
  }
}

// ---------------- 128xBN MFMA GEMM, global_load_lds staging ---------------
// A bf16 [M][1024], Bt bf16 [N][1024]. LDS unpadded rowsx64, XOR-swizzled:
// LDS chunk (r, c) holds global chunk (r, c ^ (r&7)) -> conflict-free b128
// frag reads while staging stays wave-contiguous for the DMA.
// Wave layout: wm=(w&1)*64, wn=(w>>1)*(BN/2); 4 m-frags x (BN/32) n-frags.
// MODE 0 (BN=128): epilogue scatters qkv into Q(pre-scaled)/K [B][H][N][64],
//                  Vt [B][H][64][N]
// MODE 1 (BN=128): epilogue adds f32 bias, writes f32 [M][1024]
//   [R8 lesson: BN=64 halves FLOPs/block but keeps the full A-staging K-loop
//    -> per-output latency doubles. Keep BN=128.]
template <int MODE, int BN>
__global__ __launch_bounds__(256) void gemm128(const bf16_t* __restrict__ A,
                                               const bf16_t* __restrict__ Bt,
                                               bf16_t* __restrict__ Qb,
                                               bf16_t* __restrict__ Kb,
                                               bf16_t* __restrict__ Vtb,
                                               const float* __restrict__ bias,
                                               float* __restrict__ Out) {
  constexpr int K = 1024;
  constexpr int NT = BN / 32;       // B n-frags per wave
  constexpr int NB = BN / 32;       // B staging chunks per thread
  __shared__ __align__(16) bf16_t As[128 * 64];
  __shared__ __align__(16) bf16_t Bs[BN * 64];
  const int m0 = blockIdx.y * 128, n0 = blockIdx.x * BN;
  const int tid = threadIdx.x;
  const int w = tid >> 6, l = tid & 63;
  const int lr = l & 15, lq = l >> 4;
  const int lrx = lr & 7;
  const int wm = (w & 1) * 64, wn = (w >> 1) * (BN / 2);
  // staging: chunk c = i*256+tid covers row r=c>>3, source chunk (c&7)^(r&7)
  int sR[4], sC[4];
#pragma unroll
  for (int i = 0; i < 4; i++) {
    sR[i] = (i * 256 + tid) >> 3;
    sC[i] = ((tid & 7) ^ (sR[i] & 7)) * 8;
  }
  f32x4 acc[4][NT] = {};

  for (int k0 = 0; k0 < K; k0 += 64) {
#pragma unroll
    for (int i = 0; i < 4; i++) {
      const int ldsoff = (i * 256 + w * 64) * 8;
      GL2LDS(&A[(size_t)(m0 + sR[i]) * K + k0 + sC[i]], &As[ldsoff]);
    }
#pragma unroll
    for (int i = 0; i < NB; i++) {
      const int ldsoff = (i * 256 + w * 64) * 8;
      GL2LDS(&Bt[(size_t)(n0 + sR[i]) * K + k0 + sC[i]], &Bs[ldsoff]);
    }
    __syncthreads();
#pragma unroll
    for (int ks = 0; ks < 2; ks++) {
      const int g = ks * 4 + lq;
      const int sw = ((g ^ lrx) << 3);
      bf16x8 af[4], bfr[NT];
#pragma unroll
      for (int mt = 0; mt < 4; mt++)
        af[mt] = *(const bf16x8*)&As[((wm + mt * 16 + lr) << 6) + sw];
#pragma unroll
      for (int nt = 0; nt < NT; nt++)
        bfr[nt] = *(const bf16x8*)&Bs[((wn + nt * 16 + lr) << 6) + sw];
#pragma unroll
      for (int mt = 0; mt < 4; mt++)
#pragma unroll
        for (int nt = 0; nt < NT; nt++)
          acc[mt][nt] = __builtin_amdgcn_mfma_f32_16x16x32_bf16(af[mt], bfr[nt],
                                                                acc[mt][nt], 0, 0, 0);
    }
    __syncthreads();
  }

#pragma unroll
  for (int mt = 0; mt < 4; mt++)
#pragma unroll
    for (int nt = 0; nt < NT; nt++)
#pragma unroll
      for (int i = 0; i < 4; i++) {
        int m = m0 + wm + mt * 16 + lq * 4 + i;   // C/D: row=(lane>>4)*4+i
        int c = n0 + wn + nt * 16 + lr;           //      col=lane&15
        float v = acc[mt][nt][i];
        if (MODE == 1) {
          Out[(size_t)m * 1024 + c] = v + bias[c];
        } else {
          int b = m >> 10, n = m & 1023;
          int which = c >> 10, cc = c & 1023;
          int hh = cc >> 6, d = cc & 63;
          size_t qk = ((size_t)((b * 16 + hh) * 1024 + n)) * 64 + d;
          if (which == 0)
            Qb[qk] = (bf16_t)(v * (0.125f * LOG2E));  // fold softmax scale+log2e
          else if (which == 1)
            Kb[qk] = (bf16_t)v;
          else
            Vtb[((size_t)((b * 16 + hh) * 64 + d)) * 1024 + n] = (bf16_t)v;
        }
      }
}

// ---------------- flash attention v5: 512 threads, 256 q/block ------------
// 1 block = (b, h, 256-query tile); 8 waves x 32 queries (2 m-frags each).
// Block remap: bid = qt*128 + (b*16+h); same-(b,h) blocks are 128 apart
// (128 % 8 == 0 -> same XCD round-robin) -> KV L2 locality preserved.
// K/V staged via global_load_lds (1 DMA per K + 1 per V per thread/iter)
// into unpadded 64-stride LDS with XOR source swizzle; double-buffered.
// Q pre-scaled by 0.125*log2e -> p = exp2(s). Rowsum via ones-B-frag MFMA.
#define PS 76
__global__ __launch_bounds__(512) void attn256(const bf16_t* __restrict__ Qb,
                                               const bf16_t* __restrict__ Kb,
                                               const bf16_t* __restrict__ Vtb,
                                               bf16_t* __restrict__ Ob) {
  __shared__ __align__(16) bf16_t Ks[2][64 * 64];
  __shared__ __align__(16) bf16_t Vs[2][64 * 64];
  __shared__ __align__(16) bf16_t Pl[8 * 32 * PS];
  const int bid = blockIdx.x;
  const int qt = bid >> 7, idx = bid & 127;  // XCD-locality remap
  const int h = idx & 15, b = idx >> 4;
  const bf16_t* Qh = Qb + (size_t)((b * 16 + h) * 1024) * 64;
  const bf16_t* Kh = Kb + (size_t)((b * 16 + h) * 1024) * 64;
  const bf16_t* Vh = Vtb + (size_t)((b * 16 + h) * 64) * 1024;  // [64][1024]
  const int tid = threadIdx.x, w = tid >> 6, l = tid & 63;
  const int lr = l & 15, lq = l >> 4;
  const int lrx = lr & 7;
  const int q0 = qt * 256 + w * 32;

  bf16x8 onesf;
#pragma unroll
  for (int i = 0; i < 8; i++) onesf[i] = (lr == 0) ? (bf16_t)1.0f : (bf16_t)0.0f;

  // staging: 512 threads cover all 512 chunks of a 64x64 tile; thread ->
  // chunk tid, row sr=tid>>3, source col-chunk swizzled by row&7.
  const int sr = tid >> 3;
  const int scc = ((tid & 7) ^ (sr & 7)) * 8;
  const int ldsW = w * 512;  // wave chunk-base (elems)

  bf16x8 qf[2][2];
#pragma unroll
  for (int mt = 0; mt < 2; mt++)
#pragma unroll
    for (int ks = 0; ks < 2; ks++)
      qf[mt][ks] = *(const bf16x8*)&Qh[(size_t)(q0 + mt * 16 + lr) * 64 + ks * 32 + lq * 8];

  // prologue: DMA tile 0 into buf 0
  GL2LDS(&Kh[(size_t)sr * 64 + scc], &Ks[0][ldsW]);
  GL2LDS(&Vh[(size_t)sr * 1024 + scc], &Vs[0][ldsW]);
  __syncthreads();

  f32x4 o[2][4] = {};
  f32x4 o5[2] = {};
  bf16_t* pw = &Pl[w * 32 * PS];

  for (int it = 0; it < 16; ++it) {
    const int buf = it & 1;
    if (it < 15) {  // DMA next tile into the other buffer
      const int jn = (it + 1) * 64;
      GL2LDS(&Kh[(size_t)(jn + sr) * 64 + scc], &Ks[buf ^ 1][ldsW]);
      GL2LDS(&Vh[(size_t)sr * 1024 + jn + scc], &Vs[buf ^ 1][ldsW]);
    }
    // S = Q K^T  (2 m-tiles x 4 n-tiles), swizzled frag reads
    f32x4 s[2][4] = {};
#pragma unroll
    for (int ks = 0; ks < 2; ks++) {
      const int sw = (((ks * 4 + lq) ^ lrx) << 3);
#pragma unroll
      for (int nt = 0; nt < 4; nt++) {
        bf16x8 kf = *(const bf16x8*)&Ks[buf][((nt * 16 + lr) << 6) + sw];
#pragma unroll
        for (int mt = 0; mt < 2; mt++)
          s[mt][nt] = __builtin_amdgcn_mfma_f32_16x16x32_bf16(qf[mt][ks], kf, s[mt][nt], 0, 0, 0);
      }
    }
    // p = exp2(s); pack to wave-private LDS in A-layout
#pragma unroll
    for (int mt = 0; mt < 2; mt++)
#pragma unroll
      for (int nt = 0; nt < 4; nt++)
#pragma unroll
        for (int i = 0; i < 4; i++)
          pw[(mt * 16 + lq * 4 + i) * PS + nt * 16 + lr] = (bf16_t)exp2f(s[mt][nt][i]);
    // O += P V ; o5 += P * ones. In-wave LDS RAW ordered by lgkmcnt.
#pragma unroll
    for (int ks = 0; ks < 2; ks++) {
      const int sw = (((ks * 4 + lq) ^ lrx) << 3);
      bf16x8 af[2];
#pragma unroll
      for (int mt = 0; mt < 2; mt++)
        af[mt] = *(const bf16x8*)&pw[(mt * 16 + lr) * PS + ks * 32 + lq * 8];
#pragma unroll
      for (int nt = 0; nt < 4; nt++) {
        bf16x8 vf = *(const bf16x8*)&Vs[buf][((nt * 16 + lr) << 6) + sw];
#pragma unroll
        for (int mt = 0; mt < 2; mt++)
          o[mt][nt] = __builtin_amdgcn_mfma_f32_16x16x32_bf16(af[mt], vf, o[mt][nt], 0, 0, 0);
      }
#pragma unroll
      for (int mt = 0; mt < 2; mt++)
        o5[mt] = __builtin_amdgcn_mfma_f32_16x16x32_bf16(af[mt], onesf, o5[mt], 0, 0, 0);
    }
    __syncthreads();  // drains DMA (vmcnt) + LDS; flips buffers
  }
  // epilogue: broadcast denominator from col-0 lanes, divide, store
#pragma unroll
  for (int mt = 0; mt < 2; mt++)
#pragma unroll
    for (int i = 0; i < 4; i++) {
      float lsum = __shfl(o5[mt][i], lq * 16);  // lane (lq,lr=0) holds rowsum
      float inv = 1.0f / lsum;
      int grow = b * 1024 + q0 + mt * 16 + lq * 4 + i;
#pragma unroll
      for (int nt = 0; nt < 4; nt++) {
        int col = h * 64 + nt * 16 + lr;
        Ob[(size_t)grow * 1024 + col] = (bf16_t)(o[mt][nt][i] * inv);
      }
    }
}

extern "C" void kernel_launch(void* const* d_in, const int* in_sizes, int n_in,
                              void* d_out, int out_size, void* d_ws, size_t ws_size,
                              hipStream_t stream) {
  const float* x     = (const float*)d_in[0];  // [8,1024,1024] f32
  const float* w_qkv = (const float*)d_in[1];  // [1024,3072] f32
  const float* w_out = (const float*)d_in[2];  // [1024,1024] f32
  const float* b_out = (const float*)d_in[3];  // [1024] f32
  float* out = (float*)d_out;                  // [8,1024,1024] f32

  bf16_t* ws = (bf16_t*)d_ws;
  const size_t SZ = (size_t)8 * 1024 * 1024;  // elems per 16MB buffer
  bf16_t* Qb  = ws;            // [B][H][N][64]  (pre-scaled)
  bf16_t* Kb  = Qb + SZ;       // [B][H][N][64]
  bf16_t* Vtb = Kb + SZ;       // [B][H][64][N]
  bf16_t* Ob  = Vtb + SZ;      // [B*N][H*64]; also aliases Xb (dead after gemm0)
  bf16_t* Wqt = Ob + SZ;       // [3072][1024]
  bf16_t* Wot = Wqt + (size_t)3072 * 1024;  // [1024][1024]
  bf16_t* Xb  = Ob;            // x as bf16 [8192][1024]
  // total ws use: 72 MB

  hipLaunchKernelGGL(convert_f32_bf16, dim3(4096), dim3(256), 0, stream, x, Xb);
  hipLaunchKernelGGL(transpose_f32_bf16, dim3(48, 16), dim3(64, 4), 0, stream,
                     w_qkv, Wqt, 1024, 3072);
  hipLaunchKernelGGL(transpose_f32_bf16, dim3(16, 16), dim3(64, 4), 0, stream,
                     w_out, Wot, 1024, 1024);
  hipLaunchKernelGGL((gemm128<0, 128>), dim3(24, 64), dim3(256), 0, stream,
                     Xb, Wqt, Qb, Kb, Vtb, (const float*)nullptr, (float*)nullptr);
  hipLaunchKernelGGL(attn256, dim3(512), dim3(512), 0, stream, Qb, Kb, Vtb, Ob);
  hipLaunchKernelGGL((gemm128<1, 128>), dim3(8, 64), dim3(256), 0, stream,
                     Ob, Wot, (bf16_t*)nullptr, (bf16_t*)nullptr, (bf16_t*)nullptr,
                     b_out, out);
}